// Round 2
// baseline (45.452 us; speedup 1.0000x reference)
//
#include <hip/hip_runtime.h>

#define N 768
#define H 128
#define NM1 767

// ---------------- p0: W1T[m][k] = W1[k][m]   (W1:[128][256] -> W1T:[256][128]) ----------------
__global__ __launch_bounds__(256) void p0_transpose(const float* __restrict__ W1,
                                                    float* __restrict__ W1T) {
  const int g = blockIdx.x * 256 + threadIdx.x;   // 8192 float4 ids
  const float4 v = ((const float4*)W1)[g];
  const int k = g >> 6;            // W1 row (0..127)
  const int m = (g & 63) << 2;     // starting column
  W1T[(size_t)(m + 0) * H + k] = v.x;
  W1T[(size_t)(m + 1) * H + k] = v.y;
  W1T[(size_t)(m + 2) * H + k] = v.z;
  W1T[(size_t)(m + 3) * H + k] = v.w;
}

// ---------------- p1: U = z @ W1a^T ; Vb = z @ W1b^T + b1  (coalesced via W1T) ----------------
#define P1R 4
__global__ __launch_bounds__(256) void p1_kernel(
    const float* __restrict__ z, const float* __restrict__ W1T,
    const float* __restrict__ b1, float* __restrict__ U, float* __restrict__ Vb) {
  __shared__ __align__(16) float zsh[P1R][H];
  const int t = threadIdx.x;
  const int rbase = blockIdx.x * P1R;
  if (t < P1R * (H / 4)) {
    const int r = t >> 5, c4 = t & 31;
    ((float4*)zsh[r])[c4] = ((const float4*)(z + (size_t)(rbase + r) * H))[c4];
  }
  __syncthreads();
  const int q = t & 31;            // k-quad (0..31)
  const int half = (t >> 5) & 1;   // 0 -> U, 1 -> Vb
  const int r = t >> 6;            // 0..3 (wave-uniform)
  const float4* __restrict__ wt = (const float4*)(W1T + (size_t)half * H * H) + q;
  float4 acc = {0.f, 0.f, 0.f, 0.f};
#pragma unroll
  for (int m = 0; m < H; m += 4) {
    const float4 zq = *(const float4*)&zsh[r][m];   // wave-uniform broadcast
    const float4 w0 = wt[(size_t)(m + 0) * 32];
    const float4 w1 = wt[(size_t)(m + 1) * 32];
    const float4 w2 = wt[(size_t)(m + 2) * 32];
    const float4 w3 = wt[(size_t)(m + 3) * 32];
    acc.x = fmaf(w0.x, zq.x, acc.x); acc.y = fmaf(w0.y, zq.x, acc.y);
    acc.z = fmaf(w0.z, zq.x, acc.z); acc.w = fmaf(w0.w, zq.x, acc.w);
    acc.x = fmaf(w1.x, zq.y, acc.x); acc.y = fmaf(w1.y, zq.y, acc.y);
    acc.z = fmaf(w1.z, zq.y, acc.z); acc.w = fmaf(w1.w, zq.y, acc.w);
    acc.x = fmaf(w2.x, zq.z, acc.x); acc.y = fmaf(w2.y, zq.z, acc.y);
    acc.z = fmaf(w2.z, zq.z, acc.z); acc.w = fmaf(w2.w, zq.z, acc.w);
    acc.x = fmaf(w3.x, zq.w, acc.x); acc.y = fmaf(w3.y, zq.w, acc.y);
    acc.z = fmaf(w3.z, zq.w, acc.z); acc.w = fmaf(w3.w, zq.w, acc.w);
  }
  float4 bias = {0.f, 0.f, 0.f, 0.f};
  if (half) bias = ((const float4*)b1)[q];
  float* dst = half ? Vb : U;
  float4 outv = {acc.x + bias.x, acc.y + bias.y, acc.z + bias.z, acc.w + bias.w};
  *(float4*)&dst[(size_t)(rbase + r) * H + 4 * q] = outv;
}

// ---------------- p2: out[i,j] = sum_k relu(U[i,k]+Vb[j,k]) * w2[k] + b2 ----------------
#define TI 48
#define TJ 48
#define LDSW (H + 4)  // pad -> row shift of 4 banks: conflict-free/2-way b128 reads
__global__ __launch_bounds__(256) void p2_kernel(
    const float* __restrict__ U, const float* __restrict__ Vb,
    const float* __restrict__ w2, const float* __restrict__ b2,
    float* __restrict__ out) {
  __shared__ __align__(16) float ush[TI * LDSW];
  __shared__ __align__(16) float vsh[TJ * LDSW];
  const int t = threadIdx.x;
  const int bi = (blockIdx.x >> 4) * TI;
  const int bj = (blockIdx.x & 15) * TJ;
#pragma unroll
  for (int l = t; l < TI * (H / 4); l += 256) {
    const int r = l >> 5, c4 = l & 31;
    *(float4*)&ush[r * LDSW + c4 * 4] = ((const float4*)(U  + (size_t)(bi + r) * H))[c4];
    *(float4*)&vsh[r * LDSW + c4 * 4] = ((const float4*)(Vb + (size_t)(bj + r) * H))[c4];
  }
  __syncthreads();
  const int tx = t & 15, ty = t >> 4;
  float acc[3][3] = {};
#pragma unroll 8
  for (int k = 0; k < H; k += 4) {
    const float4 w = *(const float4*)(w2 + k);  // uniform -> scalar load
    float4 uu[3], vv[3];
#pragma unroll
    for (int r = 0; r < 3; ++r) uu[r] = *(const float4*)&ush[(ty + 16 * r) * LDSW + k];
#pragma unroll
    for (int r = 0; r < 3; ++r) vv[r] = *(const float4*)&vsh[(tx + 16 * r) * LDSW + k];
#pragma unroll
    for (int a = 0; a < 3; ++a)
#pragma unroll
      for (int b = 0; b < 3; ++b) {
        acc[a][b] = fmaf(fmaxf(uu[a].x + vv[b].x, 0.f), w.x, acc[a][b]);
        acc[a][b] = fmaf(fmaxf(uu[a].y + vv[b].y, 0.f), w.y, acc[a][b]);
        acc[a][b] = fmaf(fmaxf(uu[a].z + vv[b].z, 0.f), w.z, acc[a][b]);
        acc[a][b] = fmaf(fmaxf(uu[a].w + vv[b].w, 0.f), w.w, acc[a][b]);
      }
  }
  const float bb = b2[0];
#pragma unroll
  for (int a = 0; a < 3; ++a) {
    const int i = bi + ty + 16 * a;
#pragma unroll
    for (int b = 0; b < 3; ++b) {
      const int j = bj + tx + 16 * b;
      if (i != j) out[(size_t)i * NM1 + j - (j > i ? 1 : 0)] = acc[a][b] + bb;
    }
  }
}

extern "C" void kernel_launch(void* const* d_in, const int* in_sizes, int n_in,
                              void* d_out, int out_size, void* d_ws, size_t ws_size,
                              hipStream_t stream) {
  const float* z  = (const float*)d_in[0];
  const float* W1 = (const float*)d_in[1];
  const float* b1 = (const float*)d_in[2];
  const float* W2 = (const float*)d_in[3];
  const float* b2 = (const float*)d_in[4];
  float* U   = (float*)d_ws;
  float* Vb  = U + N * H;
  float* W1T = Vb + N * H;
  p0_transpose<<<32, 256, 0, stream>>>(W1, W1T);
  p1_kernel<<<N / P1R, 256, 0, stream>>>(z, W1T, b1, U, Vb);
  p2_kernel<<<(N / TI) * (N / TJ), 256, 0, stream>>>(U, Vb, W2, b2, (float*)d_out);
}

// Round 3
// 28.995 us; speedup vs baseline: 1.5676x; 1.5676x over previous
//
#include <hip/hip_runtime.h>

#define N 768
#define H 128
#define NM1 767

// ---------------- p0: W1T[m][k] = W1[k][m]   (W1:[128][256] -> W1T:[256][128]) ----------------
__global__ __launch_bounds__(256) void p0_transpose(const float* __restrict__ W1,
                                                    float* __restrict__ W1T) {
  const int g = blockIdx.x * 256 + threadIdx.x;   // 8192 float4 ids
  const float4 v = ((const float4*)W1)[g];
  const int k = g >> 6;            // W1 row (0..127)
  const int m = (g & 63) << 2;     // starting column
  W1T[(size_t)(m + 0) * H + k] = v.x;
  W1T[(size_t)(m + 1) * H + k] = v.y;
  W1T[(size_t)(m + 2) * H + k] = v.z;
  W1T[(size_t)(m + 3) * H + k] = v.w;
}

// ---------------- p1: U = z @ W1a^T ; Vb = z @ W1b^T + b1  (coalesced via W1T) ----------------
#define P1R 4
__global__ __launch_bounds__(256) void p1_kernel(
    const float* __restrict__ z, const float* __restrict__ W1T,
    const float* __restrict__ b1, float* __restrict__ U, float* __restrict__ Vb) {
  __shared__ __align__(16) float zsh[P1R][H];
  const int t = threadIdx.x;
  const int rbase = blockIdx.x * P1R;
  if (t < P1R * (H / 4)) {
    const int r = t >> 5, c4 = t & 31;
    ((float4*)zsh[r])[c4] = ((const float4*)(z + (size_t)(rbase + r) * H))[c4];
  }
  __syncthreads();
  const int q = t & 31;            // k-quad (0..31)
  const int half = (t >> 5) & 1;   // 0 -> U, 1 -> Vb
  const int r = t >> 6;            // 0..3 (wave-uniform)
  const float4* __restrict__ wt = (const float4*)(W1T + (size_t)half * H * H) + q;
  float4 acc = {0.f, 0.f, 0.f, 0.f};
#pragma unroll 4                    // cap: full unroll spilled (VGPR=256, 43MB scratch)
  for (int m = 0; m < H; m += 4) {
    const float4 zq = *(const float4*)&zsh[r][m];   // wave-uniform broadcast
    const float4 w0 = wt[(size_t)(m + 0) * 32];
    const float4 w1 = wt[(size_t)(m + 1) * 32];
    const float4 w2 = wt[(size_t)(m + 2) * 32];
    const float4 w3 = wt[(size_t)(m + 3) * 32];
    acc.x = fmaf(w0.x, zq.x, acc.x); acc.y = fmaf(w0.y, zq.x, acc.y);
    acc.z = fmaf(w0.z, zq.x, acc.z); acc.w = fmaf(w0.w, zq.x, acc.w);
    acc.x = fmaf(w1.x, zq.y, acc.x); acc.y = fmaf(w1.y, zq.y, acc.y);
    acc.z = fmaf(w1.z, zq.y, acc.z); acc.w = fmaf(w1.w, zq.y, acc.w);
    acc.x = fmaf(w2.x, zq.z, acc.x); acc.y = fmaf(w2.y, zq.z, acc.y);
    acc.z = fmaf(w2.z, zq.z, acc.z); acc.w = fmaf(w2.w, zq.z, acc.w);
    acc.x = fmaf(w3.x, zq.w, acc.x); acc.y = fmaf(w3.y, zq.w, acc.y);
    acc.z = fmaf(w3.z, zq.w, acc.z); acc.w = fmaf(w3.w, zq.w, acc.w);
  }
  float4 bias = {0.f, 0.f, 0.f, 0.f};
  if (half) bias = ((const float4*)b1)[q];
  float* dst = half ? Vb : U;
  float4 outv = {acc.x + bias.x, acc.y + bias.y, acc.z + bias.z, acc.w + bias.w};
  *(float4*)&dst[(size_t)(rbase + r) * H + 4 * q] = outv;
}

// ---------------- p2: out[i,j] = sum_k relu(U[i,k]+Vb[j,k]) * w2[k] + b2 ----------------
#define TI 48
#define TJ 48
#define LDSW (H + 4)  // pad -> row shift of 4 banks: conflict-free/2-way b128 reads
__global__ __launch_bounds__(256) void p2_kernel(
    const float* __restrict__ U, const float* __restrict__ Vb,
    const float* __restrict__ w2, const float* __restrict__ b2,
    float* __restrict__ out) {
  __shared__ __align__(16) float ush[TI * LDSW];
  __shared__ __align__(16) float vsh[TJ * LDSW];
  const int t = threadIdx.x;
  const int bi = (blockIdx.x >> 4) * TI;
  const int bj = (blockIdx.x & 15) * TJ;
#pragma unroll
  for (int l = t; l < TI * (H / 4); l += 256) {
    const int r = l >> 5, c4 = l & 31;
    *(float4*)&ush[r * LDSW + c4 * 4] = ((const float4*)(U  + (size_t)(bi + r) * H))[c4];
    *(float4*)&vsh[r * LDSW + c4 * 4] = ((const float4*)(Vb + (size_t)(bj + r) * H))[c4];
  }
  __syncthreads();
  const int tx = t & 15, ty = t >> 4;
  float acc[3][3] = {};
#pragma unroll 8
  for (int k = 0; k < H; k += 4) {
    const float4 w = *(const float4*)(w2 + k);  // uniform -> scalar load
    float4 uu[3], vv[3];
#pragma unroll
    for (int r = 0; r < 3; ++r) uu[r] = *(const float4*)&ush[(ty + 16 * r) * LDSW + k];
#pragma unroll
    for (int r = 0; r < 3; ++r) vv[r] = *(const float4*)&vsh[(tx + 16 * r) * LDSW + k];
#pragma unroll
    for (int a = 0; a < 3; ++a)
#pragma unroll
      for (int b = 0; b < 3; ++b) {
        acc[a][b] = fmaf(fmaxf(uu[a].x + vv[b].x, 0.f), w.x, acc[a][b]);
        acc[a][b] = fmaf(fmaxf(uu[a].y + vv[b].y, 0.f), w.y, acc[a][b]);
        acc[a][b] = fmaf(fmaxf(uu[a].z + vv[b].z, 0.f), w.z, acc[a][b]);
        acc[a][b] = fmaf(fmaxf(uu[a].w + vv[b].w, 0.f), w.w, acc[a][b]);
      }
  }
  const float bb = b2[0];
#pragma unroll
  for (int a = 0; a < 3; ++a) {
    const int i = bi + ty + 16 * a;
#pragma unroll
    for (int b = 0; b < 3; ++b) {
      const int j = bj + tx + 16 * b;
      if (i != j) out[(size_t)i * NM1 + j - (j > i ? 1 : 0)] = acc[a][b] + bb;
    }
  }
}

extern "C" void kernel_launch(void* const* d_in, const int* in_sizes, int n_in,
                              void* d_out, int out_size, void* d_ws, size_t ws_size,
                              hipStream_t stream) {
  const float* z  = (const float*)d_in[0];
  const float* W1 = (const float*)d_in[1];
  const float* b1 = (const float*)d_in[2];
  const float* W2 = (const float*)d_in[3];
  const float* b2 = (const float*)d_in[4];
  float* U   = (float*)d_ws;
  float* Vb  = U + N * H;
  float* W1T = Vb + N * H;
  p0_transpose<<<32, 256, 0, stream>>>(W1, W1T);
  p1_kernel<<<N / P1R, 256, 0, stream>>>(z, W1T, b1, U, Vb);
  p2_kernel<<<(N / TI) * (N / TJ), 256, 0, stream>>>(U, Vb, W2, b2, (float*)d_out);
}